// Round 1
// baseline (24.585 us; speedup 1.0000x reference)
//
#include <hip/hip_runtime.h>

// pose3d_calibration: B=262144 poses, J=15 joints.
// out[0] = mean over (B,6) of (|bone_l|^2 - |bone_r|^2)^2
// out[1] = mean over (B,2,15) of (project(R^T (X - C)) - pose2d)^2
//
// Memory-bound streaming reduction: 348 B/pose in, 8 B total out.
// f64 math for the projection path: proj is dominated by near-zero-z samples
// (catastrophic cancellation in z), so we match the numpy reference at full
// precision instead of gambling on f32 rounding order.

__global__ __launch_bounds__(256) void pose_calib_main(
    const float* __restrict__ pose3d,   // (B,3,15)
    const float* __restrict__ pose2d,   // (B,2,15)
    const float* __restrict__ Rd,       // (B,3,3)
    const float* __restrict__ Cd,       // (B,3,1)
    double* __restrict__ partial,       // (gridDim.x, 2)
    int B)
{
    const int b = blockIdx.x * blockDim.x + threadIdx.x;
    double sym_d = 0.0, proj_d = 0.0;

    if (b < B) {
        const float* p3 = pose3d + (size_t)b * 45;
        float X[45];
        #pragma unroll
        for (int i = 0; i < 45; ++i) X[i] = p3[i];

        // bones: LEFT  [[1,5],[5,6],[6,7],[14,11],[11,12],[12,13]]
        //        RIGHT [[1,2],[2,3],[3,4],[14,8],[8,9],[9,10]]
        const int lb0[6] = {1,5,6,14,11,12};
        const int lb1[6] = {5,6,7,11,12,13};
        const int rb0[6] = {1,2,3,14,8,9};
        const int rb1[6] = {2,3,4,8,9,10};
        #pragma unroll
        for (int k = 0; k < 6; ++k) {
            double ll = 0.0, lr = 0.0;
            #pragma unroll
            for (int c = 0; c < 3; ++c) {
                double dl = (double)X[c*15 + lb0[k]] - (double)X[c*15 + lb1[k]];
                double dr = (double)X[c*15 + rb0[k]] - (double)X[c*15 + rb1[k]];
                ll += dl * dl;
                lr += dr * dr;
            }
            double d = ll - lr;
            sym_d += d * d;
        }

        // P[i] = sum_j R[j,i] * (X[j] - C[j])   (R^T @ (X - C)); R_CAM = I
        const float* Rp = Rd + (size_t)b * 9;
        const float* Cp = Cd + (size_t)b * 3;
        const double R00 = Rp[0], R01 = Rp[1], R02 = Rp[2];
        const double R10 = Rp[3], R11 = Rp[4], R12 = Rp[5];
        const double R20 = Rp[6], R21 = Rp[7], R22 = Rp[8];
        const double C0 = Cp[0], C1 = Cp[1], C2 = Cp[2];

        const float* p2 = pose2d + (size_t)b * 30;
        #pragma unroll
        for (int j = 0; j < 15; ++j) {
            double q0 = (double)X[j]      - C0;
            double q1 = (double)X[15 + j] - C1;
            double q2 = (double)X[30 + j] - C2;
            double P0 = R00*q0 + R10*q1 + R20*q2;
            double P1 = R01*q0 + R11*q1 + R21*q2;
            double P2 = R02*q0 + R12*q1 + R22*q2;
            double rz = 1.0 / P2;
            double u = 512.0 * P0 * rz + 512.0;
            double v = 512.0 * P1 * rz + 256.0;
            double du = u - (double)p2[j];
            double dv = v - (double)p2[15 + j];
            proj_d += du*du + dv*dv;
        }
    }

    // block reduction: wave shfl (64-lane) -> LDS across 4 waves
    #pragma unroll
    for (int off = 32; off > 0; off >>= 1) {
        sym_d  += __shfl_down(sym_d,  off, 64);
        proj_d += __shfl_down(proj_d, off, 64);
    }
    __shared__ double s_sym[4], s_proj[4];
    const int lane = threadIdx.x & 63;
    const int wid  = threadIdx.x >> 6;
    if (lane == 0) { s_sym[wid] = sym_d; s_proj[wid] = proj_d; }
    __syncthreads();
    if (threadIdx.x == 0) {
        partial[2*(size_t)blockIdx.x]     = s_sym[0] + s_sym[1] + s_sym[2] + s_sym[3];
        partial[2*(size_t)blockIdx.x + 1] = s_proj[0] + s_proj[1] + s_proj[2] + s_proj[3];
    }
}

__global__ __launch_bounds__(256) void pose_calib_finish(
    const double* __restrict__ partial, int nblk,
    float* __restrict__ out, double inv_n_sym, double inv_n_proj)
{
    double ss = 0.0, pp = 0.0;
    for (int i = threadIdx.x; i < nblk; i += 256) {
        ss += partial[2*(size_t)i];
        pp += partial[2*(size_t)i + 1];
    }
    #pragma unroll
    for (int off = 32; off > 0; off >>= 1) {
        ss += __shfl_down(ss, off, 64);
        pp += __shfl_down(pp, off, 64);
    }
    __shared__ double s_s[4], s_p[4];
    const int lane = threadIdx.x & 63;
    const int wid  = threadIdx.x >> 6;
    if (lane == 0) { s_s[wid] = ss; s_p[wid] = pp; }
    __syncthreads();
    if (threadIdx.x == 0) {
        double S = s_s[0] + s_s[1] + s_s[2] + s_s[3];
        double P = s_p[0] + s_p[1] + s_p[2] + s_p[3];
        out[0] = (float)(S * inv_n_sym);
        out[1] = (float)(P * inv_n_proj);
    }
}

extern "C" void kernel_launch(void* const* d_in, const int* in_sizes, int n_in,
                              void* d_out, int out_size, void* d_ws, size_t ws_size,
                              hipStream_t stream) {
    const float* pose3d = (const float*)d_in[0];
    const float* pose2d = (const float*)d_in[1];
    const float* Rd     = (const float*)d_in[2];
    const float* Cd     = (const float*)d_in[3];

    const int B = in_sizes[3] / 3;           // C_drone is (B,3,1)
    const int threads = 256;
    const int nblk = (B + threads - 1) / threads;

    double* partial = (double*)d_ws;         // nblk*2 doubles (16 KB @ B=262144)

    pose_calib_main<<<nblk, threads, 0, stream>>>(pose3d, pose2d, Rd, Cd, partial, B);
    pose_calib_finish<<<1, threads, 0, stream>>>(
        partial, nblk, (float*)d_out,
        1.0 / ((double)B * 6.0), 1.0 / ((double)B * 30.0));
}